// Round 4
// baseline (544.857 us; speedup 1.0000x reference)
//
#include <hip/hip_runtime.h>
#include <math.h>

// CognitiveRouter: module routing (4) + grouped expert routing (16), combined
// hierarchical probs, top-4 + renorm.  T=32768, D=1536, fp32 in/out.
//
// R4 = R3 structure with the split-K exchange bug fixed.
// R3 bug: exchange wrote myStage[lane*21+e] (max idx 1342) into a 1088-float
// wave region -> cross-wave corruption.  Now: dedicated transposed exchange
// buffer xch[e*512 + tid] (conflict-free, properly sized) overlaid on the
// staging memory via a union, with a barrier before the overlay is written.
//
// Perf structure (R3 theory, untested until now):
//  1. Weights as per-lane VMEM broadcast loads (vmcnt path, deep queue).
//  2. hs staged with non-temporal loads (read-once stream; don't evict
//     the 123 KB weight table from L1/L2).
//  3. Split-K 8 (512-thr blocks, CPW=192): 16 waves/CU, 4 waves/SIMD.
//  4. No in-loop barriers (wave-private staging), register prefetch.

#define DD 1536
#define NM 4
#define NE 16
#define NW 20          // 16 expert rows + 4 module rows
#define RPB 64         // rows per block (lane = row)
#define NWAVE 8        // split-K ways
#define NTHR (NWAVE * 64)
#define CPW 192        // cols per wave (DD / 8)
#define CHUNK 16       // cols staged per iteration
#define LSTRIDE 17     // CHUNK + 1 (odd -> conflict-free ds_read)
#define WAVE_LDS (RPB * LSTRIDE)  // 1088 floats per wave staging region

typedef float v4f __attribute__((ext_vector_type(4)));

__device__ __forceinline__ v4f nt_load4(const float* p) {
    return __builtin_nontemporal_load((const v4f*)p);   // global_load nt
}

union SharedMem {
    float stage[NWAVE * WAVE_LDS];   // 8704 floats (K-loop staging)
    float xch[NW * NTHR];            // 10240 floats (epilogue exchange)
};

__global__ __launch_bounds__(NTHR, 4)
void router_kernel(const float* __restrict__ hs,
                   const float* __restrict__ Wm,
                   const float* __restrict__ We,
                   float* __restrict__ out,
                   int T)
{
    __shared__ SharedMem sm;          // 40960 B
    const int tid  = threadIdx.x;
    const int wv   = tid >> 6;
    const int lane = tid & 63;
    const int rowBlock = blockIdx.x * RPB;
    const int colStart = wv * CPW;

    float acc[NW];
#pragma unroll
    for (int e = 0; e < NW; e++) acc[e] = 0.f;

    // staging map: 4 lanes cover one row's 16-col chunk (4x float4);
    // lane -> (row srow + 16i, col group scol).
    const int srow = lane >> 2;          // 0..15
    const int scol = (lane & 3) << 2;    // 0,4,8,12
    const float* hsBase = hs + (size_t)(rowBlock + srow) * DD + colStart + scol;
    float* myStage = &sm.stage[wv * WAVE_LDS];

    // prefetch chunk 0 into registers (non-temporal: hs is a read-once stream)
    v4f buf[4];
#pragma unroll
    for (int i = 0; i < 4; i++)
        buf[i] = nt_load4(hsBase + (size_t)(i * 16) * DD);

    for (int c = 0; c < CPW; c += CHUNK) {
        // ---- commit prefetched tile to wave-private LDS ----
#pragma unroll
        for (int i = 0; i < 4; i++) {
            float* dst = &myStage[(srow + i * 16) * LSTRIDE + scol];
            dst[0] = buf[i].x; dst[1] = buf[i].y; dst[2] = buf[i].z; dst[3] = buf[i].w;
        }
        // ---- prefetch next chunk while computing this one ----
        if (c + CHUNK < CPW) {
#pragma unroll
            for (int i = 0; i < 4; i++)
                buf[i] = nt_load4(hsBase + (size_t)(i * 16) * DD + (c + CHUNK));
        }
        // ---- compute: 4 x 4-col steps, 20 dot-product accumulators ----
#pragma unroll
        for (int g = 0; g < 4; g++) {
            const float* hp = &myStage[lane * LSTRIDE + (g << 2)];
            float h0 = hp[0], h1 = hp[1], h2 = hp[2], h3 = hp[3];
            const int col = colStart + c + (g << 2);
#pragma unroll
            for (int e = 0; e < NE; e++) {
                v4f w4 = *(const v4f*)(We + (size_t)e * DD + col);  // broadcast
                acc[e] += h0 * w4.x + h1 * w4.y + h2 * w4.z + h3 * w4.w;
            }
#pragma unroll
            for (int m = 0; m < NM; m++) {
                v4f w4 = *(const v4f*)(Wm + (size_t)m * DD + col);
                acc[NE + m] += h0 * w4.x + h1 * w4.y + h2 * w4.z + h3 * w4.w;
            }
        }
        // no barrier: wave-private staging, wave program order suffices
    }

    // ---- split-K partial exchange: xch[e][tid], conflict-free ----
    __syncthreads();   // staging regions are dead for ALL waves before overlay
#pragma unroll
    for (int e = 0; e < NW; e++) sm.xch[e * NTHR + tid] = acc[e];
    __syncthreads();

    if (wv == 0) {
        float logit[NW];
#pragma unroll
        for (int e = 0; e < NW; e++) {
            float s = 0.f;
#pragma unroll
            for (int w = 0; w < NWAVE; w++)
                s += sm.xch[e * NTHR + w * 64 + lane];
            logit[e] = s;
        }

        // module softmax over logit[16..19]
        float mmax = logit[16];
#pragma unroll
        for (int m = 1; m < NM; m++) mmax = fmaxf(mmax, logit[16 + m]);
        float mexp[NM], msum = 0.f;
#pragma unroll
        for (int m = 0; m < NM; m++) { mexp[m] = expf(logit[16 + m] - mmax); msum += mexp[m]; }

        // per-module expert softmax, combined probs
        float comb[NE];
#pragma unroll
        for (int m = 0; m < NM; m++) {
            float mprob = mexp[m] / msum;
            float emax = logit[m * 4];
#pragma unroll
            for (int j = 1; j < 4; j++) emax = fmaxf(emax, logit[m * 4 + j]);
            float ee[4], esum = 0.f;
#pragma unroll
            for (int j = 0; j < 4; j++) { ee[j] = expf(logit[m * 4 + j] - emax); esum += ee[j]; }
            float scale = mprob / esum;
#pragma unroll
            for (int j = 0; j < 4; j++) comb[m * 4 + j] = ee[j] * scale;
        }

        const int row = rowBlock + lane;
        float4* cw = (float4*)(out + (size_t)row * 16);
        cw[0] = make_float4(comb[0],  comb[1],  comb[2],  comb[3]);
        cw[1] = make_float4(comb[4],  comb[5],  comb[6],  comb[7]);
        cw[2] = make_float4(comb[8],  comb[9],  comb[10], comb[11]);
        cw[3] = make_float4(comb[12], comb[13], comb[14], comb[15]);

        // top-4, descending, strict > so lowest index wins ties (lax.top_k)
        float tv[4]; int ti[4];
        unsigned mask = 0;
#pragma unroll
        for (int k = 0; k < 4; k++) {
            float best = -1.f; int bi = 0;
#pragma unroll
            for (int i = 0; i < NE; i++) {
                bool avail = !((mask >> i) & 1u);
                if (avail && comb[i] > best) { best = comb[i]; bi = i; }
            }
            tv[k] = best; ti[k] = bi; mask |= 1u << bi;
        }
        float s = tv[0] + tv[1] + tv[2] + tv[3] + 1e-8f;

        const size_t wOff = (size_t)T * 16;          // top_k_weights region
        const size_t iOff = (size_t)T * 20;          // top_k_indices region
        float4* ww = (float4*)(out + wOff + (size_t)row * 4);
        *ww = make_float4(tv[0] / s, tv[1] / s, tv[2] / s, tv[3] / s);
        float4* iw = (float4*)(out + iOff + (size_t)row * 4);
        *iw = make_float4((float)ti[0], (float)ti[1], (float)ti[2], (float)ti[3]);
    }
}

extern "C" void kernel_launch(void* const* d_in, const int* in_sizes, int n_in,
                              void* d_out, int out_size, void* d_ws, size_t ws_size,
                              hipStream_t stream)
{
    const float* hs = (const float*)d_in[0];   // (T, 1536)
    const float* Wm = (const float*)d_in[1];   // (4, 1536)
    const float* We = (const float*)d_in[2];   // (16, 1536)
    float* out = (float*)d_out;
    const int T = in_sizes[0] / DD;            // 32768
    router_kernel<<<T / RPB, NTHR, 0, stream>>>(hs, Wm, We, out, T);
}

// Round 5
// 296.217 us; speedup vs baseline: 1.8394x; 1.8394x over previous
//
#include <hip/hip_runtime.h>
#include <math.h>

// CognitiveRouter: module routing (4) + grouped expert routing (16), combined
// hierarchical probs, top-4 + renorm.  T=32768, D=1536, fp32 in/out.
//
// R5 (R4 post-mortem: 443 MB scratch-spill writes per dispatch -- compiler
// hoisted 20 in-flight VMEM weight loads, hit the launch_bounds VGPR cap,
// and spilled acc[] every chunk; VALUBusy collapsed to 11.6%).
// Changes:
//  1. Weights staged into LDS once per chunk (10 coalesced loads/lane-wave),
//     then read per g-step as wave-uniform BROADCAST ds_read_b128 (~2-4 cyc,
//     conflict-free, short in-order lgkm latency -> no register hoisting).
//     VMEM ops in the hot loop drop from 20/g-step to amortized ~1.2.
//  2. LSTRIDE 17 -> 20: keeps 16 B alignment so b128 LDS ops stay single
//     instructions (17*4 B offsets forced splits -> R4's 1.57M conflicts).
//  3. No __launch_bounds__ min-occupancy clamp (let RA use registers, no
//     spill), no non-temporal flags.
//  4. Keep: split-K 8 across waves, wave-private staging (no in-loop
//     barriers), register prefetch, R4's verified transposed exchange.

#define DD 1536
#define NM 4
#define NE 16
#define NW 20          // 16 expert rows + 4 module rows
#define RPB 64         // rows per block (lane = row)
#define NWAVE 8        // split-K ways
#define NTHR (NWAVE * 64)
#define CPW 192        // cols per wave (DD / 8)
#define CHUNK 16       // cols staged per iteration
#define NCHUNK (CPW / CHUNK)
#define LSTRIDE 20     // CHUNK + 4: 16B-aligned rows, full-bank pattern
#define HS_FLOATS (RPB * LSTRIDE)   // 1280 floats
#define W_FLOATS  (NW * LSTRIDE)    // 400 floats
#define WAVE_REG  (HS_FLOATS + W_FLOATS)  // 1680 floats per wave region

typedef float v4f __attribute__((ext_vector_type(4)));

union SharedMem {
    float stage[NWAVE * WAVE_REG];   // 13440 floats (K-loop staging)
    float xch[NW * NTHR];            // 10240 floats (epilogue exchange)
};

__global__ __launch_bounds__(NTHR)
void router_kernel(const float* __restrict__ hs,
                   const float* __restrict__ Wm,
                   const float* __restrict__ We,
                   float* __restrict__ out,
                   int T)
{
    __shared__ SharedMem sm;          // 53760 B -> 2 blocks/CU fits in 160 KB
    const int tid  = threadIdx.x;
    const int wv   = tid >> 6;
    const int lane = tid & 63;
    const int rowBlock = blockIdx.x * RPB;
    const int colStart = wv * CPW;

    float acc[NW];
#pragma unroll
    for (int e = 0; e < NW; e++) acc[e] = 0.f;

    // hs staging map: 4 lanes cover one row's 16-col chunk; lane ->
    // (row srow+16i, col group scol). 4 consecutive lanes = 64 B contiguous.
    const int srow = lane >> 2;          // 0..15
    const int scol = (lane & 3) << 2;    // 0,4,8,12
    const float* hsBase = hs + (size_t)(rowBlock + srow) * DD + colStart + scol;
    float* myHs = &sm.stage[wv * WAVE_REG];
    float* myW  = myHs + HS_FLOATS;

    // weight staging map: 20 rows x 4 col-groups = 80 float4 slots.
    //   slot  = lane      (rows 0..15  -> We)
    //   slot2 = 64 + lane (rows 16..19 -> Wm), lanes 0..15 only
    const int wrow0 = lane >> 2;                       // 0..15 (We row)
    const int wgrp0 = (lane & 3) << 2;
    const float* weBase = We + (size_t)wrow0 * DD + colStart + wgrp0;
    const float* wmBase = Wm + (size_t)(lane >> 2) * DD + colStart + wgrp0; // lanes<16

    // ---- prefetch chunk 0 ----
    v4f hbuf[4], wbuf0, wbuf1;
#pragma unroll
    for (int i = 0; i < 4; i++)
        hbuf[i] = *(const v4f*)(hsBase + (size_t)(i * 16) * DD);
    wbuf0 = *(const v4f*)(weBase);
    if (lane < 16) wbuf1 = *(const v4f*)(wmBase);

    for (int c = 0; c < CPW; c += CHUNK) {
        // ---- commit prefetched tiles to wave-private LDS ----
#pragma unroll
        for (int i = 0; i < 4; i++)
            *(v4f*)&myHs[(srow + i * 16) * LSTRIDE + scol] = hbuf[i];
        *(v4f*)&myW[wrow0 * LSTRIDE + wgrp0] = wbuf0;
        if (lane < 16)
            *(v4f*)&myW[(16 + (lane >> 2)) * LSTRIDE + wgrp0] = wbuf1;

        // ---- prefetch next chunk while computing this one ----
        if (c + CHUNK < CPW) {
            const int cn = c + CHUNK;
#pragma unroll
            for (int i = 0; i < 4; i++)
                hbuf[i] = *(const v4f*)(hsBase + (size_t)(i * 16) * DD + cn);
            wbuf0 = *(const v4f*)(weBase + cn);
            if (lane < 16) wbuf1 = *(const v4f*)(wmBase + cn);
        }

        // ---- compute: 4 g-steps x (1 hs read + 20 broadcast w reads + 80 FMA)
#pragma unroll
        for (int g = 0; g < 4; g++) {
            v4f h = *(const v4f*)&myHs[lane * LSTRIDE + (g << 2)];
#pragma unroll
            for (int e = 0; e < NW; e++) {
                v4f w = *(const v4f*)&myW[e * LSTRIDE + (g << 2)]; // broadcast
                acc[e] += h.x * w.x + h.y * w.y + h.z * w.z + h.w * w.w;
            }
        }
        // no barrier: wave-private staging, wave program order suffices
    }

    // ---- split-K partial exchange: xch[e][tid], conflict-free ----
    __syncthreads();   // staging regions dead for ALL waves before overlay
#pragma unroll
    for (int e = 0; e < NW; e++) sm.xch[e * NTHR + tid] = acc[e];
    __syncthreads();

    if (wv == 0) {
        float logit[NW];
#pragma unroll
        for (int e = 0; e < NW; e++) {
            float s = 0.f;
#pragma unroll
            for (int w = 0; w < NWAVE; w++)
                s += sm.xch[e * NTHR + w * 64 + lane];
            logit[e] = s;
        }

        // module softmax over logit[16..19]
        float mmax = logit[16];
#pragma unroll
        for (int m = 1; m < NM; m++) mmax = fmaxf(mmax, logit[16 + m]);
        float mexp[NM], msum = 0.f;
#pragma unroll
        for (int m = 0; m < NM; m++) { mexp[m] = expf(logit[16 + m] - mmax); msum += mexp[m]; }

        // per-module expert softmax, combined probs
        float comb[NE];
#pragma unroll
        for (int m = 0; m < NM; m++) {
            float mprob = mexp[m] / msum;
            float emax = logit[m * 4];
#pragma unroll
            for (int j = 1; j < 4; j++) emax = fmaxf(emax, logit[m * 4 + j]);
            float ee[4], esum = 0.f;
#pragma unroll
            for (int j = 0; j < 4; j++) { ee[j] = expf(logit[m * 4 + j] - emax); esum += ee[j]; }
            float scale = mprob / esum;
#pragma unroll
            for (int j = 0; j < 4; j++) comb[m * 4 + j] = ee[j] * scale;
        }

        const int row = rowBlock + lane;
        float4* cw = (float4*)(out + (size_t)row * 16);
        cw[0] = make_float4(comb[0],  comb[1],  comb[2],  comb[3]);
        cw[1] = make_float4(comb[4],  comb[5],  comb[6],  comb[7]);
        cw[2] = make_float4(comb[8],  comb[9],  comb[10], comb[11]);
        cw[3] = make_float4(comb[12], comb[13], comb[14], comb[15]);

        // top-4, descending, strict > so lowest index wins ties (lax.top_k)
        float tv[4]; int ti[4];
        unsigned mask = 0;
#pragma unroll
        for (int k = 0; k < 4; k++) {
            float best = -1.f; int bi = 0;
#pragma unroll
            for (int i = 0; i < NE; i++) {
                bool avail = !((mask >> i) & 1u);
                if (avail && comb[i] > best) { best = comb[i]; bi = i; }
            }
            tv[k] = best; ti[k] = bi; mask |= 1u << bi;
        }
        float s = tv[0] + tv[1] + tv[2] + tv[3] + 1e-8f;

        const size_t wOff = (size_t)T * 16;          // top_k_weights region
        const size_t iOff = (size_t)T * 20;          // top_k_indices region
        float4* ww = (float4*)(out + wOff + (size_t)row * 4);
        *ww = make_float4(tv[0] / s, tv[1] / s, tv[2] / s, tv[3] / s);
        float4* iw = (float4*)(out + iOff + (size_t)row * 4);
        *iw = make_float4((float)ti[0], (float)ti[1], (float)ti[2], (float)ti[3]);
    }
}

extern "C" void kernel_launch(void* const* d_in, const int* in_sizes, int n_in,
                              void* d_out, int out_size, void* d_ws, size_t ws_size,
                              hipStream_t stream)
{
    const float* hs = (const float*)d_in[0];   // (T, 1536)
    const float* Wm = (const float*)d_in[1];   // (4, 1536)
    const float* We = (const float*)d_in[2];   // (16, 1536)
    float* out = (float*)d_out;
    const int T = in_sizes[0] / DD;            // 32768
    router_kernel<<<T / RPB, NTHR, 0, stream>>>(hs, Wm, We, out, T);
}